// Round 8
// baseline (31.296 us; speedup 1.0000x reference)
//
#include <hip/hip_runtime.h>

// ROI-Align (bilinear, half-pixel) — B=1, H=W=128, C=512, POOL=7, N ROIs.
// Output layout: (N, 1, 7, 7, C) flat = ((roi*49 + py*7 + px) * C + c).
//
// Round-8 (= round-5 resubmit; rounds 5-7 hit infra failures): 16-way
// channel partition, epoch-split across the grid.
//   - chunk c ∈ [0,16); XCD = blockIdx.x % 8 (round-robin dispatch heuristic).
//   - First half of the grid runs chunks 0-7 (one per XCD), second half runs
//     chunks 8-15. Each XCD's concurrent read working set is one
//     128x128x32 fp32 sub-map = 2 MiB, comfortably resident in its 4 MiB L2
//     (round-4's exactly-4-MiB working set sat at the capacity edge).
//   - Non-temporal output stores keep the streaming writes from evicting
//     the resident sub-map.
// Block = 256 threads = 32 bins x 8 lanes; lane = one float4 of the 32-ch chunk.

#define POOLN 7
#define FM_H 128
#define FM_W 128
#define FM_C 512
#define NXCD 8
#define NCHUNK 16
#define CHUNK_C (FM_C / NCHUNK)      // 32 channels per chunk
#define BINS_PER_BLOCK 32            // 256 threads / 8 lanes

typedef float f32x4 __attribute__((ext_vector_type(4)));

__global__ __launch_bounds__(256) void roi_align_kernel(
    const float* __restrict__ fm,
    const int* __restrict__ rois,
    float* __restrict__ out,
    int n_bins,
    int half_grid)
{
    int bidx = blockIdx.x;
    int chunk_base = 0;
    if (bidx >= half_grid) { bidx -= half_grid; chunk_base = NXCD; }
    const int chunk  = (bidx & (NXCD - 1)) + chunk_base;  // 0..15; XCD = chunk%8
    const int group  = bidx >> 3;
    const int lane_c = threadIdx.x & 7;                   // float4 index within chunk
    const int bin    = group * BINS_PER_BLOCK + (threadIdx.x >> 3);
    if (bin >= n_bins) return;

    const int roi = bin / 49;
    const int rem = bin - roi * 49;
    const int py  = rem / 7;
    const int px  = rem - py * 7;

    const int4 r = reinterpret_cast<const int4*>(rois)[roi];
    const int x1 = r.x, y1 = r.y, x2 = r.z, y2 = r.w;

    // y coordinate (half-pixel, clipped to [0, size-1], then + start)
    const float sizy = (float)(y2 - y1);
    float cy = ((float)py + 0.5f) * (sizy / (float)POOLN) - 0.5f;
    cy = fminf(fmaxf(cy, 0.0f), sizy - 1.0f);
    const float ys = cy + (float)y1;
    const int   y0 = (int)floorf(ys);
    const int   yb = min(y0 + 1, y2 - 1);
    const float wy = ys - (float)y0;

    // x coordinate
    const float sizx = (float)(x2 - x1);
    float cx = ((float)px + 0.5f) * (sizx / (float)POOLN) - 0.5f;
    cx = fminf(fmaxf(cx, 0.0f), sizx - 1.0f);
    const float xs = cx + (float)x1;
    const int   x0 = (int)floorf(xs);
    const int   xb = min(x0 + 1, x2 - 1);
    const float wx = xs - (float)x0;

    const int coff = chunk * CHUNK_C + lane_c * 4;

    const f32x4 a = *reinterpret_cast<const f32x4*>(fm + (size_t)(y0 * FM_W + x0) * FM_C + coff);
    const f32x4 b = *reinterpret_cast<const f32x4*>(fm + (size_t)(y0 * FM_W + xb) * FM_C + coff);
    const f32x4 d = *reinterpret_cast<const f32x4*>(fm + (size_t)(yb * FM_W + x0) * FM_C + coff);
    const f32x4 e = *reinterpret_cast<const f32x4*>(fm + (size_t)(yb * FM_W + xb) * FM_C + coff);

    const f32x4 top = a + (b - a) * wx;
    const f32x4 bot = d + (e - d) * wx;
    const f32x4 res = top + (bot - top) * wy;

    f32x4* o = reinterpret_cast<f32x4*>(out + (size_t)bin * FM_C + coff);
    __builtin_nontemporal_store(res, o);
}

extern "C" void kernel_launch(void* const* d_in, const int* in_sizes, int n_in,
                              void* d_out, int out_size, void* d_ws, size_t ws_size,
                              hipStream_t stream) {
    const float* fm   = (const float*)d_in[0];
    const int*   rois = (const int*)d_in[1];
    float*       out  = (float*)d_out;

    const int N      = in_sizes[1] / 4;                   // 1024 ROIs
    const int n_bins = N * POOLN * POOLN;                 // 50176
    const int groups = (n_bins + BINS_PER_BLOCK - 1) / BINS_PER_BLOCK;  // 1568
    const int half   = groups * NXCD;                     // 12544
    dim3 grid(half * 2);                                  // 25088 blocks
    roi_align_kernel<<<grid, 256, 0, stream>>>(fm, rois, out, n_bins, half);
}